// Round 8
// baseline (220.572 us; speedup 1.0000x reference)
//
#include <hip/hip_runtime.h>
#include <hip/hip_bf16.h>

// Quantum layer: 4 qubits, 2 layers. Everything after the RY(x) encoding is a
// fixed unitary U (weights are batch-constant). Each output q is multilinear
// in (1, cos th_p, sin th_p) per qubit: 81 coefficients per output.
// qsetup (4 blocks) computes C as [4][27] float4 (triple + pad) into d_ws.
//
// Delivery-path history (measured): per-lane VMEM reload ~20-22us (R1/R4);
// LDS ~52us (R3, also BW-floor ~22us); scalar s_load ~42us (R6, and R7 where
// the compiler auto-scalarized uniform float4 loads: VGPR=24/SGPR=112).
// Fix: coefficients live in VGPRs, loaded ONCE per thread per q via inline
// asm (compiler cannot scalarize asm), reused across EPT=4 elements.

typedef float f32x4 __attribute__((ext_vector_type(4)));

__global__ __launch_bounds__(256) void qsetup(const float* __restrict__ w,
                                              float* __restrict__ C) {
    __shared__ float Ur[16][16];   // [row k][col j]
    __shared__ float Ui[16][16];
    __shared__ float M[16][16];
    const int q = blockIdx.x;      // output qubit 0..3
    const int tid = threadIdx.x;

    // ---- step 1: threads 0..15 each simulate one basis column of U ----
    if (tid < 16) {
        float re[16], im[16];
#pragma unroll
        for (int i = 0; i < 16; ++i) { re[i] = (i == tid) ? 1.0f : 0.0f; im[i] = 0.0f; }

#pragma unroll
        for (int ly = 0; ly < 2; ++ly) {
#pragma unroll
            for (int qq = 0; qq < 4; ++qq) {
                const int mm = 8 >> qq;
                float th, c, s;
                // RX(w[ly][qq][0])
                th = w[(ly * 4 + qq) * 3 + 0] * 0.5f; c = __cosf(th); s = __sinf(th);
#pragma unroll
                for (int i = 0; i < 16; ++i) if (!(i & mm)) {
                    const int j = i | mm;
                    float r0 = re[i], i0 = im[i], r1 = re[j], i1 = im[j];
                    re[i] = c * r0 + s * i1;  im[i] = c * i0 - s * r1;
                    re[j] = s * i0 + c * r1;  im[j] = -s * r0 + c * i1;
                }
                // RY(w[ly][qq][1])
                th = w[(ly * 4 + qq) * 3 + 1] * 0.5f; c = __cosf(th); s = __sinf(th);
#pragma unroll
                for (int i = 0; i < 16; ++i) if (!(i & mm)) {
                    const int j = i | mm;
                    float r0 = re[i], i0 = im[i], r1 = re[j], i1 = im[j];
                    re[i] = c * r0 - s * r1;  im[i] = c * i0 - s * i1;
                    re[j] = s * r0 + c * r1;  im[j] = s * i0 + c * i1;
                }
                // RZ(w[ly][qq][2])
                th = w[(ly * 4 + qq) * 3 + 2] * 0.5f; c = __cosf(th); s = __sinf(th);
#pragma unroll
                for (int i = 0; i < 16; ++i) if (!(i & mm)) {
                    const int j = i | mm;
                    float r0 = re[i], i0 = im[i], r1 = re[j], i1 = im[j];
                    re[i] = c * r0 + s * i0;  im[i] = c * i0 - s * r0;
                    re[j] = c * r1 - s * i1;  im[j] = c * i1 + s * r1;
                }
            }
            // CNOT chain (q,q+1)
#pragma unroll
            for (int qq = 0; qq < 3; ++qq) {
                const int mc = 8 >> qq, mt = 8 >> (qq + 1);
#pragma unroll
                for (int i = 0; i < 16; ++i) if ((i & mc) && !(i & mt)) {
                    const int j = i | mt;
                    float tr = re[i]; re[i] = re[j]; re[j] = tr;
                    float ti = im[i]; im[i] = im[j]; im[j] = ti;
                }
            }
        }
#pragma unroll
        for (int k = 0; k < 16; ++k) { Ur[k][tid] = re[k]; Ui[k][tid] = im[k]; }
    }
    __syncthreads();

    // ---- step 2: M[j][l] = sum_k sign_q(k) Re(U[k,j] conj(U[k,l])) ----
    {
        const int j = tid >> 4, l = tid & 15;
        float acc = 0.0f;
#pragma unroll
        for (int k = 0; k < 16; ++k) {
            const float sgn = ((k >> (3 - q)) & 1) ? -1.0f : 1.0f;
            acc += sgn * (Ur[k][j] * Ur[k][l] + Ui[k][j] * Ui[k][l]);
        }
        M[j][l] = acc;
    }
    __syncthreads();

    // ---- step 3: project onto (1,cos,sin)^{(x)4} basis ----
    // Layout: C[(q*27 + T)*4 + m], T = (i*3+j)*3+k, m = 0..2, m=3 zero pad.
    if (tid < 108) {
        if (tid < 81) {
            int ap[4];
            ap[0] = tid / 27; ap[1] = (tid / 9) % 3; ap[2] = (tid / 3) % 3; ap[3] = tid % 3;
            float acc = 0.0f;
            for (int m = 0; m < 16; ++m) {
                int j = 0, l = 0; float sgn = 1.0f;
#pragma unroll
                for (int p = 0; p < 4; ++p) {
                    const int o = (m >> (3 - p)) & 1;
                    int jb = o, lb = (ap[p] == 2) ? (o ^ 1) : o;
                    if (ap[p] == 1 && o) sgn = -sgn;
                    j = (j << 1) | jb; l = (l << 1) | lb;
                }
                acc += sgn * M[j][l];
            }
            C[(q * 27 + tid / 3) * 4 + (tid % 3)] = acc * 0.0625f;
        } else {
            C[(q * 27 + (tid - 81)) * 4 + 3] = 0.0f;   // pad lane
        }
    }
}

#define EPT 4

__global__ __launch_bounds__(256, 2) void qmain(const float* __restrict__ x,
                                                const float* __restrict__ C,
                                                float* __restrict__ out, int B) {
    const int tid = blockIdx.x * 256 + threadIdx.x;
    const int total = gridDim.x * 256;

    // ---- x loads + transcendentals for all EPT elements up front ----
    float cg[EPT][4], sg[EPT][4];
    bool valid[EPT];
#pragma unroll
    for (int e = 0; e < EPT; ++e) {
        const int b = tid + e * total;
        valid[e] = (b < B);
        float4 xv = make_float4(0.f, 0.f, 0.f, 0.f);
        if (valid[e]) xv = *reinterpret_cast<const float4*>(x + (size_t)b * 8);
        float xs[4] = {xv.x, xv.y, xv.z, xv.w};
#pragma unroll
        for (int q = 0; q < 4; ++q) {
            const float ex = __expf(2.0f * xs[q]);
            const float t = 1.0f - __fdividef(2.0f, ex + 1.0f);   // tanh(x)
            __sincosf(3.1415f * t, &sg[e][q], &cg[e][q]);
        }
    }

    float ev[EPT][4];
#pragma unroll
    for (int q = 0; q < 4; ++q) {
        // ---- pull this output's 27 coefficient triples into VGPRs ----
        // One asm block: 27 global_load_dwordx4 + single vmcnt(0). Outputs
        // early-clobber so none alias the address pair (round-5 lesson).
        // Compiler cannot scalarize asm -> guaranteed VMEM -> VGPR.
        const f32x4* cq = reinterpret_cast<const f32x4*>(C) + q * 27;
        f32x4 k0,k1,k2,k3,k4,k5,k6,k7,k8,k9,k10,k11,k12,k13,
              k14,k15,k16,k17,k18,k19,k20,k21,k22,k23,k24,k25,k26;
        asm volatile(
            "global_load_dwordx4 %0,  %[a], off\n\t"
            "global_load_dwordx4 %1,  %[a], off offset:16\n\t"
            "global_load_dwordx4 %2,  %[a], off offset:32\n\t"
            "global_load_dwordx4 %3,  %[a], off offset:48\n\t"
            "global_load_dwordx4 %4,  %[a], off offset:64\n\t"
            "global_load_dwordx4 %5,  %[a], off offset:80\n\t"
            "global_load_dwordx4 %6,  %[a], off offset:96\n\t"
            "global_load_dwordx4 %7,  %[a], off offset:112\n\t"
            "global_load_dwordx4 %8,  %[a], off offset:128\n\t"
            "global_load_dwordx4 %9,  %[a], off offset:144\n\t"
            "global_load_dwordx4 %10, %[a], off offset:160\n\t"
            "global_load_dwordx4 %11, %[a], off offset:176\n\t"
            "global_load_dwordx4 %12, %[a], off offset:192\n\t"
            "global_load_dwordx4 %13, %[a], off offset:208\n\t"
            "global_load_dwordx4 %14, %[a], off offset:224\n\t"
            "global_load_dwordx4 %15, %[a], off offset:240\n\t"
            "global_load_dwordx4 %16, %[a], off offset:256\n\t"
            "global_load_dwordx4 %17, %[a], off offset:272\n\t"
            "global_load_dwordx4 %18, %[a], off offset:288\n\t"
            "global_load_dwordx4 %19, %[a], off offset:304\n\t"
            "global_load_dwordx4 %20, %[a], off offset:320\n\t"
            "global_load_dwordx4 %21, %[a], off offset:336\n\t"
            "global_load_dwordx4 %22, %[a], off offset:352\n\t"
            "global_load_dwordx4 %23, %[a], off offset:368\n\t"
            "global_load_dwordx4 %24, %[a], off offset:384\n\t"
            "global_load_dwordx4 %25, %[a], off offset:400\n\t"
            "global_load_dwordx4 %26, %[a], off offset:416\n\t"
            "s_waitcnt vmcnt(0)"
            : "=&v"(k0), "=&v"(k1), "=&v"(k2), "=&v"(k3), "=&v"(k4),
              "=&v"(k5), "=&v"(k6), "=&v"(k7), "=&v"(k8), "=&v"(k9),
              "=&v"(k10), "=&v"(k11), "=&v"(k12), "=&v"(k13), "=&v"(k14),
              "=&v"(k15), "=&v"(k16), "=&v"(k17), "=&v"(k18), "=&v"(k19),
              "=&v"(k20), "=&v"(k21), "=&v"(k22), "=&v"(k23), "=&v"(k24),
              "=&v"(k25), "=&v"(k26)
            : [a] "v"(cq)
            : "memory");
#define KT(n) ((n) == 0 ? k0 : (n) == 1 ? k1 : (n) == 2 ? k2 : (n) == 3 ? k3 : \
               (n) == 4 ? k4 : (n) == 5 ? k5 : (n) == 6 ? k6 : (n) == 7 ? k7 : \
               (n) == 8 ? k8 : (n) == 9 ? k9 : (n) == 10 ? k10 : (n) == 11 ? k11 : \
               (n) == 12 ? k12 : (n) == 13 ? k13 : (n) == 14 ? k14 : (n) == 15 ? k15 : \
               (n) == 16 ? k16 : (n) == 17 ? k17 : (n) == 18 ? k18 : (n) == 19 ? k19 : \
               (n) == 20 ? k20 : (n) == 21 ? k21 : (n) == 22 ? k22 : (n) == 23 ? k23 : \
               (n) == 24 ? k24 : (n) == 25 ? k25 : k26)

        // ---- register-lean Horner for all EPT elements vs VGPR coeffs ----
        float acc[EPT], ai[EPT], aj[EPT];
#pragma unroll
        for (int i = 0; i < 3; ++i) {
#pragma unroll
            for (int j = 0; j < 3; ++j) {
#pragma unroll
                for (int k = 0; k < 3; ++k) {
                    const f32x4 cv = KT((i * 3 + j) * 3 + k);
#pragma unroll
                    for (int e = 0; e < EPT; ++e) {
                        const float t = __fmaf_rn(cv[2], sg[e][3],
                                        __fmaf_rn(cv[1], cg[e][3], cv[0]));
                        if (k == 0)      aj[e] = t;
                        else if (k == 1) aj[e] = __fmaf_rn(t, cg[e][2], aj[e]);
                        else             aj[e] = __fmaf_rn(t, sg[e][2], aj[e]);
                    }
                }
#pragma unroll
                for (int e = 0; e < EPT; ++e) {
                    if (j == 0)      ai[e] = aj[e];
                    else if (j == 1) ai[e] = __fmaf_rn(aj[e], cg[e][1], ai[e]);
                    else             ai[e] = __fmaf_rn(aj[e], sg[e][1], ai[e]);
                }
            }
#pragma unroll
            for (int e = 0; e < EPT; ++e) {
                if (i == 0)      acc[e] = ai[e];
                else if (i == 1) acc[e] = __fmaf_rn(ai[e], cg[e][0], acc[e]);
                else             acc[e] = __fmaf_rn(ai[e], sg[e][0], acc[e]);
            }
        }
#pragma unroll
        for (int e = 0; e < EPT; ++e) ev[e][q] = acc[e];
#undef KT
    }

#pragma unroll
    for (int e = 0; e < EPT; ++e) {
        const int b = tid + e * total;
        if (valid[e])
            *reinterpret_cast<float4*>(out + (size_t)b * 4) =
                make_float4(ev[e][0], ev[e][1], ev[e][2], ev[e][3]);
    }
}

extern "C" void kernel_launch(void* const* d_in, const int* in_sizes, int n_in,
                              void* d_out, int out_size, void* d_ws, size_t ws_size,
                              hipStream_t stream) {
    const float* x = (const float*)d_in[0];       // (B, 8) f32
    const float* w = (const float*)d_in[1];       // (2, 4, 3) f32
    float* out = (float*)d_out;                   // (B, 4) f32
    float* C = (float*)d_ws;                      // 4*27 float4 scratch

    const int B = in_sizes[0] / 8;

    qsetup<<<4, 256, 0, stream>>>(w, C);

    const int threads_needed = (B + EPT - 1) / EPT;
    const int grid = (threads_needed + 255) / 256;
    qmain<<<grid, 256, 0, stream>>>(x, C, out, B);
}

// Round 9
// 37.734 us; speedup vs baseline: 5.8455x; 5.8455x over previous
//
#include <hip/hip_runtime.h>
#include <hip/hip_bf16.h>

// Quantum layer: 4 qubits, 2 layers. Everything after the RY(x) encoding is a
// fixed unitary U (weights are batch-constant). Each output q is multilinear
// in (1, cos th_p, sin th_p) per qubit: 81 coefficients per output.
// qsetup (4 blocks) computes C[4][81] from weights into d_ws.
//
// Delivery-path history (measured):
//   per-lane VMEM reload      ~20-22us (R1/R4)
//   LDS broadcast             ~52us (R3; LDS-BW floor alone ~22us)
//   scalar, load-use dist ~2  ~42us (R6 volatile/elem, R7 auto-scalarized)
//   VGPR cache via 27-wide asm: spilled -> 500MB scratch, 220us (R8)
// This round: scalar path with load-use distance = one q-block. Per q: ONE
// s_load batch (81 dwords -> SGPRs, one lgkm wait), then EPT=4 elements of
// pure-FMA Horner. c0 slots copied to VGPR (27 v_mov, e-invariant) so every
// FMA carries <=1 SGPR operand (no hidden mov tax).

typedef float f32x16 __attribute__((ext_vector_type(16)));

__global__ __launch_bounds__(256) void qsetup(const float* __restrict__ w,
                                              float* __restrict__ C) {
    __shared__ float Ur[16][16];   // [row k][col j]
    __shared__ float Ui[16][16];
    __shared__ float M[16][16];
    const int q = blockIdx.x;      // output qubit 0..3
    const int tid = threadIdx.x;

    // ---- step 1: threads 0..15 each simulate one basis column of U ----
    if (tid < 16) {
        float re[16], im[16];
#pragma unroll
        for (int i = 0; i < 16; ++i) { re[i] = (i == tid) ? 1.0f : 0.0f; im[i] = 0.0f; }

#pragma unroll
        for (int ly = 0; ly < 2; ++ly) {
#pragma unroll
            for (int qq = 0; qq < 4; ++qq) {
                const int mm = 8 >> qq;
                float th, c, s;
                // RX(w[ly][qq][0])
                th = w[(ly * 4 + qq) * 3 + 0] * 0.5f; c = __cosf(th); s = __sinf(th);
#pragma unroll
                for (int i = 0; i < 16; ++i) if (!(i & mm)) {
                    const int j = i | mm;
                    float r0 = re[i], i0 = im[i], r1 = re[j], i1 = im[j];
                    re[i] = c * r0 + s * i1;  im[i] = c * i0 - s * r1;
                    re[j] = s * i0 + c * r1;  im[j] = -s * r0 + c * i1;
                }
                // RY(w[ly][qq][1])
                th = w[(ly * 4 + qq) * 3 + 1] * 0.5f; c = __cosf(th); s = __sinf(th);
#pragma unroll
                for (int i = 0; i < 16; ++i) if (!(i & mm)) {
                    const int j = i | mm;
                    float r0 = re[i], i0 = im[i], r1 = re[j], i1 = im[j];
                    re[i] = c * r0 - s * r1;  im[i] = c * i0 - s * i1;
                    re[j] = s * r0 + c * r1;  im[j] = s * i0 + c * i1;
                }
                // RZ(w[ly][qq][2])
                th = w[(ly * 4 + qq) * 3 + 2] * 0.5f; c = __cosf(th); s = __sinf(th);
#pragma unroll
                for (int i = 0; i < 16; ++i) if (!(i & mm)) {
                    const int j = i | mm;
                    float r0 = re[i], i0 = im[i], r1 = re[j], i1 = im[j];
                    re[i] = c * r0 + s * i0;  im[i] = c * i0 - s * r0;
                    re[j] = c * r1 - s * i1;  im[j] = c * i1 + s * r1;
                }
            }
            // CNOT chain (q,q+1)
#pragma unroll
            for (int qq = 0; qq < 3; ++qq) {
                const int mc = 8 >> qq, mt = 8 >> (qq + 1);
#pragma unroll
                for (int i = 0; i < 16; ++i) if ((i & mc) && !(i & mt)) {
                    const int j = i | mt;
                    float tr = re[i]; re[i] = re[j]; re[j] = tr;
                    float ti = im[i]; im[i] = im[j]; im[j] = ti;
                }
            }
        }
#pragma unroll
        for (int k = 0; k < 16; ++k) { Ur[k][tid] = re[k]; Ui[k][tid] = im[k]; }
    }
    __syncthreads();

    // ---- step 2: M[j][l] = sum_k sign_q(k) Re(U[k,j] conj(U[k,l])) ----
    {
        const int j = tid >> 4, l = tid & 15;
        float acc = 0.0f;
#pragma unroll
        for (int k = 0; k < 16; ++k) {
            const float sgn = ((k >> (3 - q)) & 1) ? -1.0f : 1.0f;
            acc += sgn * (Ur[k][j] * Ur[k][l] + Ui[k][j] * Ui[k][l]);
        }
        M[j][l] = acc;
    }
    __syncthreads();

    // ---- step 3: project onto (1,cos,sin)^{(x)4} basis: 81 coeffs ----
    if (tid < 81) {
        int ap[4];
        ap[0] = tid / 27; ap[1] = (tid / 9) % 3; ap[2] = (tid / 3) % 3; ap[3] = tid % 3;
        float acc = 0.0f;
        for (int m = 0; m < 16; ++m) {
            int j = 0, l = 0; float sgn = 1.0f;
#pragma unroll
            for (int p = 0; p < 4; ++p) {
                const int o = (m >> (3 - p)) & 1;
                int jb = o, lb = (ap[p] == 2) ? (o ^ 1) : o;
                if (ap[p] == 1 && o) sgn = -sgn;
                j = (j << 1) | jb; l = (l << 1) | lb;
            }
            acc += sgn * M[j][l];
        }
        C[q * 81 + tid] = acc * 0.0625f;
    }
}

#define EPT 4

__global__ __launch_bounds__(256) void qmain(const float* __restrict__ x,
                                             const float* __restrict__ C,
                                             float* __restrict__ out, int B) {
    const int tid = blockIdx.x * 256 + threadIdx.x;
    const int total = gridDim.x * 256;

    // ---- x loads + transcendentals for all EPT elements up front ----
    float cg[EPT][4], sg[EPT][4];
    bool valid[EPT];
#pragma unroll
    for (int e = 0; e < EPT; ++e) {
        const int b = tid + e * total;
        valid[e] = (b < B);
        float4 xv = make_float4(0.f, 0.f, 0.f, 0.f);
        if (valid[e]) xv = *reinterpret_cast<const float4*>(x + (size_t)b * 8);
        float xs[4] = {xv.x, xv.y, xv.z, xv.w};
#pragma unroll
        for (int q = 0; q < 4; ++q) {
            const float ex = __expf(2.0f * xs[q]);
            const float t = 1.0f - __fdividef(2.0f, ex + 1.0f);   // tanh(x)
            __sincosf(3.1415f * t, &sg[e][q], &cg[e][q]);
        }
    }

    float ev[EPT][4];
#pragma unroll
    for (int q = 0; q < 4; ++q) {
        // ---- 81 coefficients -> SGPRs, ONE batch, ONE lgkm wait per q ----
        // "=&s" early-clobber: outputs must not alias the pointer input
        // (round-5 lesson); waitcnt inside the block (rule-#18 safe).
        const float* cqp = C + q * 81;
        f32x16 sA, sB, sCv, sD, sE; float sF;
        asm volatile(
            "s_load_dwordx16 %0, %6, 0x0\n\t"
            "s_load_dwordx16 %1, %6, 0x40\n\t"
            "s_load_dwordx16 %2, %6, 0x80\n\t"
            "s_load_dwordx16 %3, %6, 0xc0\n\t"
            "s_load_dwordx16 %4, %6, 0x100\n\t"
            "s_load_dword    %5, %6, 0x140\n\t"
            "s_waitcnt lgkmcnt(0)"
            : "=&s"(sA), "=&s"(sB), "=&s"(sCv), "=&s"(sD), "=&s"(sE), "=&s"(sF)
            : "s"(cqp));
#define CQ(e) ((e) < 16 ? sA[(e)] : (e) < 32 ? sB[(e) - 16] : (e) < 48 ? sCv[(e) - 32] \
               : (e) < 64 ? sD[(e) - 48] : (e) < 80 ? sE[(e) - 64] : sF)

        // ---- c0 slots -> VGPR (e-invariant; keeps every FMA at <=1 SGPR) ----
        float c0v[27];
#pragma unroll
        for (int T = 0; T < 27; ++T) {
            const float s0 = CQ(3 * T);
            asm("v_mov_b32 %0, %1" : "=v"(c0v[T]) : "s"(s0));
        }

        // ---- register-lean Horner for all EPT elements ----
        float acc[EPT], ai[EPT], aj[EPT];
#pragma unroll
        for (int i = 0; i < 3; ++i) {
#pragma unroll
            for (int j = 0; j < 3; ++j) {
#pragma unroll
                for (int k = 0; k < 3; ++k) {
                    const int T = (i * 3 + j) * 3 + k;
#pragma unroll
                    for (int e = 0; e < EPT; ++e) {
                        float t = __fmaf_rn(CQ(3 * T + 1), cg[e][3], c0v[T]);
                        t = __fmaf_rn(CQ(3 * T + 2), sg[e][3], t);
                        if (k == 0)      aj[e] = t;
                        else if (k == 1) aj[e] = __fmaf_rn(t, cg[e][2], aj[e]);
                        else             aj[e] = __fmaf_rn(t, sg[e][2], aj[e]);
                    }
                }
#pragma unroll
                for (int e = 0; e < EPT; ++e) {
                    if (j == 0)      ai[e] = aj[e];
                    else if (j == 1) ai[e] = __fmaf_rn(aj[e], cg[e][1], ai[e]);
                    else             ai[e] = __fmaf_rn(aj[e], sg[e][1], ai[e]);
                }
            }
#pragma unroll
            for (int e = 0; e < EPT; ++e) {
                if (i == 0)      acc[e] = ai[e];
                else if (i == 1) acc[e] = __fmaf_rn(ai[e], cg[e][0], acc[e]);
                else             acc[e] = __fmaf_rn(ai[e], sg[e][0], acc[e]);
            }
        }
#pragma unroll
        for (int e = 0; e < EPT; ++e) ev[e][q] = acc[e];
#undef CQ
    }

#pragma unroll
    for (int e = 0; e < EPT; ++e) {
        const int b = tid + e * total;
        if (valid[e])
            *reinterpret_cast<float4*>(out + (size_t)b * 4) =
                make_float4(ev[e][0], ev[e][1], ev[e][2], ev[e][3]);
    }
}

extern "C" void kernel_launch(void* const* d_in, const int* in_sizes, int n_in,
                              void* d_out, int out_size, void* d_ws, size_t ws_size,
                              hipStream_t stream) {
    const float* x = (const float*)d_in[0];       // (B, 8) f32
    const float* w = (const float*)d_in[1];       // (2, 4, 3) f32
    float* out = (float*)d_out;                   // (B, 4) f32
    float* C = (float*)d_ws;                      // 4*81 floats scratch

    const int B = in_sizes[0] / 8;

    qsetup<<<4, 256, 0, stream>>>(w, C);

    const int threads_needed = (B + EPT - 1) / EPT;
    const int grid = (threads_needed + 255) / 256;
    qmain<<<grid, 256, 0, stream>>>(x, C, out, B);
}